// Round 1
// 149.236 us; speedup vs baseline: 1.3250x; 1.3250x over previous
//
#include <hip/hip_runtime.h>

#define Bb 4
#define Cc 256
#define Ss 256
#define Hh 128
#define Ww 128
#define Jj 8
#define HWp 16384   // H*W
#define BN_EPS 1e-5f

// ---------------- workspace byte offsets ----------------
#define WS_PS   0          // 1024 f32 partial sums; REUSED after k_build as T[256] float4
#define WS_PQ   4096       // 1024 f32 partial sumsq
#define WS_MU   10240      // mu       4*8*256 f32 (32768 B)
#define WS_LAB  43008      // labels   4*128*128 u8 (65536 B)
#define WS_WTG  108544     // Wt_gamma 2304*256 f32 (2359296 B)
#define WS_WTB  2467840    // Wt_beta  2304*256 f32
#define WS_V2   4827136    // V2 [b][tap][c][16] float2 (gamma,beta) = 1179648 B

// ---- K1 (merged prep): bn-partial | labels | mu | transpose, split by blockIdx ----
__global__ void k_prep(const float* __restrict__ fp, const float* __restrict__ sg,
                       const float* __restrict__ style, const int* __restrict__ mask,
                       const float* __restrict__ Wmu, const float* __restrict__ bmu,
                       const float* __restrict__ Wg, const float* __restrict__ Wb,
                       float* __restrict__ ws_f, unsigned char* __restrict__ labout,
                       float* __restrict__ muout,
                       float* __restrict__ wtg, float* __restrict__ wtb) {
    __shared__ float smem[1056];           // max: transpose tile 32*33
    const int t = threadIdx.x;
    const int blk = blockIdx.x;
    if (blk < 1024) {
        // per-(c,b) partial sums for BN stats
        const int c = blk >> 2, b = blk & 3;
        const float4* s4 = (const float4*)(fp + (size_t)(b * Cc + c) * HWp);
        float sum = 0.f, sq = 0.f;
        #pragma unroll
        for (int k = 0; k < 16; ++k) {
            float4 v = s4[t + k * 256];
            sum += v.x + v.y + v.z + v.w;
            sq  += v.x * v.x + v.y * v.y + v.z * v.z + v.w * v.w;
        }
        float* ls = smem;
        float* lq = smem + 256;
        ls[t] = sum; lq[t] = sq;
        __syncthreads();
        for (int off = 128; off > 0; off >>= 1) {
            if (t < off) { ls[t] += ls[t + off]; lq[t] += lq[t + off]; }
            __syncthreads();
        }
        if (t == 0) { ws_f[blk] = ls[0]; ws_f[1024 + blk] = lq[0]; }
    } else if (blk < 1280) {
        // labels from one-hot sg
        const int i = (blk - 1024) * 256 + t;
        const int b = i >> 14, p = i & (HWp - 1);
        const float* base = sg + (size_t)b * Jj * HWp + p;
        int l = 0;
        #pragma unroll
        for (int j = 0; j < Jj; ++j)
            if (base[(size_t)j * HWp] > 0.5f) l = j;
        labout[i] = (unsigned char)l;
    } else if (blk < 1312) {
        // per-(b,j) style FC + ReLU -> mu
        const int lb = blk - 1280;
        const int b = lb >> 3, j = lb & 7;
        const int sel = (mask[b * Jj + j] == 1) ? j : Jj;
        float* code = smem;
        code[t] = style[(size_t)(b * (Jj + 1) + sel) * Ss + t];
        __syncthreads();
        const float4* wrow = (const float4*)(Wmu + (size_t)(j * Ss + t) * Ss);
        const float4* c4 = (const float4*)code;
        float acc = bmu[j * Ss + t];
        #pragma unroll 8
        for (int s4i = 0; s4i < Ss / 4; ++s4i) {
            float4 w = wrow[s4i]; float4 cv = c4[s4i];
            acc += w.x * cv.x + w.y * cv.y + w.z * cv.z + w.w * cv.w;
        }
        muout[(size_t)lb * Ss + t] = fmaxf(acc, 0.f);
    } else {
        // LDS-tiled transpose [256][2304] -> [2304][256]
        const int local = blk - 1312;            // 0..1151
        const int z = local / 576;
        const int rem = local % 576;
        const int k0 = (rem % 72) * 32;
        const int r0 = (rem / 72) * 32;
        const float* in = z ? Wb : Wg;
        float* outp = z ? wtb : wtg;
        float (*tile)[33] = (float(*)[33])smem;
        const int tx = t & 31, ty = t >> 5;
        #pragma unroll
        for (int i2 = 0; i2 < 4; ++i2)
            tile[ty + 8 * i2][tx] = in[(size_t)(r0 + ty + 8 * i2) * 2304 + k0 + tx];
        __syncthreads();
        #pragma unroll
        for (int i2 = 0; i2 < 4; ++i2)
            outp[(size_t)(k0 + ty + 8 * i2) * 256 + r0 + tx] = tile[tx][ty + 8 * i2];
    }
}

// ---- K2 (merged build): block 0 = BN finalize -> T table; blocks 1..36 = V2 build ----
__global__ void k_build(const float* __restrict__ bn_g, const float* __restrict__ bn_b,
                        const float* __restrict__ bgam, const float* __restrict__ bbet,
                        const float* __restrict__ wtg, const float* __restrict__ wtb,
                        const float* __restrict__ mu, float* __restrict__ ws_f,
                        char* __restrict__ V2) {
    const int t = threadIdx.x;
    if (blockIdx.x == 0) {
        // T[c] = (scale, shift, 1 + b_gamma, b_beta); overwrites PS region (safe:
        // each thread reads exactly floats [4t,4t+4) of PS before writing them)
        float s = 0.f, q = 0.f;
        #pragma unroll
        for (int b = 0; b < 4; ++b) { s += ws_f[t * 4 + b]; q += ws_f[1024 + t * 4 + b]; }
        float mean = s * (1.f / 65536.f);
        float var  = q * (1.f / 65536.f) - mean * mean;
        float sc = bn_g[t] * rsqrtf(var + BN_EPS);
        float sh = bn_b[t] - mean * sc;
        ((float4*)ws_f)[t] = make_float4(sc, sh, 1.f + bgam[t], bbet[t]);
        return;
    }
    const int lb = blockIdx.x - 1;
    const int tap = lb % 9, b = lb / 9;
    __shared__ __align__(16) float ml[Jj * Ss];          // ml[s*8+j] = mu[b][j][s]
    for (int idx = t; idx < Jj * Ss; idx += 256)
        ml[idx] = mu[(size_t)b * Jj * Ss + (size_t)(idx & 7) * Ss + (idx >> 3)];
    __syncthreads();
    float ag[8] = {0,0,0,0,0,0,0,0}, ab[8] = {0,0,0,0,0,0,0,0};
    const float* wpg = wtg + (size_t)tap * 256 + t;
    const float* wpb = wtb + (size_t)tap * 256 + t;
    #pragma unroll 4
    for (int s = 0; s < Ss; ++s) {
        float wg = wpg[(size_t)s * 2304];
        float wb = wpb[(size_t)s * 2304];
        float4 m0 = *(const float4*)&ml[s * 8];
        float4 m1 = *(const float4*)&ml[s * 8 + 4];
        ag[0] += wg * m0.x; ab[0] += wb * m0.x;
        ag[1] += wg * m0.y; ab[1] += wb * m0.y;
        ag[2] += wg * m0.z; ab[2] += wb * m0.z;
        ag[3] += wg * m0.w; ab[3] += wb * m0.w;
        ag[4] += wg * m1.x; ab[4] += wb * m1.x;
        ag[5] += wg * m1.y; ab[5] += wb * m1.y;
        ag[6] += wg * m1.z; ab[6] += wb * m1.z;
        ag[7] += wg * m1.w; ab[7] += wb * m1.w;
    }
    // row (b,tap,c): 16 float2 slots, slot j = (gamma_j, beta_j), slots 8..15 = 0
    float4* row = (float4*)(V2 + ((size_t)((b * 9 + tap) * 256 + t) << 7));
    row[0] = make_float4(ag[0], ab[0], ag[1], ab[1]);
    row[1] = make_float4(ag[2], ab[2], ag[3], ab[3]);
    row[2] = make_float4(ag[4], ab[4], ag[5], ab[5]);
    row[3] = make_float4(ag[6], ab[6], ag[7], ab[7]);
    const float4 z4 = make_float4(0.f, 0.f, 0.f, 0.f);
    row[4] = z4; row[5] = z4; row[6] = z4; row[7] = z4;
}

// ---- K3: fused BN-apply + conv-as-gather + SPADE combine ----
// Per wave: c is uniform, w is lane. 9 uniform base ptrs + 9 per-lane j*8 voffsets;
// every channel iteration's gather folds into an imm offset (ci*128 <= 3968).
__global__ void __launch_bounds__(256, 4) k_main(
    const float* __restrict__ fp, const unsigned char* __restrict__ lab,
    const char* __restrict__ V2, const float4* __restrict__ T,
    float* __restrict__ out) {
    const int h = blockIdx.x, cc = blockIdx.y, b = blockIdx.z;
    __shared__ int labs[3][132];
    const int t = threadIdx.x;
    for (int idx = t; idx < 3 * 132; idx += 256) {
        const int r = idx / 132, col = idx % 132 - 1;
        const int hh = h - 1 + r;
        int v = 8;                        // OOB sentinel -> zero slot of V2
        if (hh >= 0 && hh < Hh && col >= 0 && col < Ww)
            v = lab[((size_t)b << 14) + (hh << 7) + col];
        labs[r][idx % 132] = v;
    }
    __syncthreads();
    const int w = t & 127;
    const int cs = __builtin_amdgcn_readfirstlane(t >> 7);   // wave-uniform
    const int c0 = cc * 64 + cs * 32;
    const char* Vb = V2 + (size_t)b * 294912 + c0 * 128;
    const char* tb[9];
    int voff[9];
    #pragma unroll
    for (int tap = 0; tap < 9; ++tap) {
        tb[tap] = Vb + tap * 32768;                   // uniform base per tap
        voff[tap] = labs[tap / 3][w + tap % 3] * 8;   // per-lane byte offset
    }
    const size_t io = (size_t)(b * Cc + c0) * HWp + (h << 7) + w;
    const float* fpp = fp + io;
    float* outp = out + io;
    const float4* Tp = T + c0;
    #pragma unroll
    for (int ci = 0; ci < 32; ++ci) {
        float g = 0.f, e = 0.f;
        #pragma unroll
        for (int tap = 0; tap < 9; ++tap) {
            const float2 v = *(const float2*)(tb[tap] + voff[tap] + ci * 128);
            g += v.x; e += v.y;
        }
        const float4 tv = Tp[ci];
        const float nf = fmaf(fpp[(size_t)ci * HWp], tv.x, tv.y);
        const float res = fmaf(nf, tv.z + g, tv.w + e);
        __builtin_nontemporal_store(res, outp + (size_t)ci * HWp);
    }
}

extern "C" void kernel_launch(void* const* d_in, const int* in_sizes, int n_in,
                              void* d_out, int out_size, void* d_ws, size_t ws_size,
                              hipStream_t stream) {
    const float* fp      = (const float*)d_in[0];
    const float* sg      = (const float*)d_in[1];
    const float* style   = (const float*)d_in[2];
    const int*   mask    = (const int*)d_in[3];
    const float* bn_g    = (const float*)d_in[4];
    const float* bn_b    = (const float*)d_in[5];
    const float* W_mu    = (const float*)d_in[6];
    const float* b_mu    = (const float*)d_in[7];
    const float* W_gam   = (const float*)d_in[8];
    const float* b_gam   = (const float*)d_in[9];
    const float* W_bet   = (const float*)d_in[10];
    const float* b_bet   = (const float*)d_in[11];
    float* out = (float*)d_out;

    char* ws = (char*)d_ws;
    float*         ws_f  = (float*)ws;
    unsigned char* labp  = (unsigned char*)(ws + WS_LAB);
    float*         mup   = (float*)(ws + WS_MU);
    float*         wtg   = (float*)(ws + WS_WTG);
    float*         wtb   = (float*)(ws + WS_WTB);
    char*          v2    = ws + WS_V2;

    k_prep<<<2464, 256, 0, stream>>>(fp, sg, style, mask, W_mu, b_mu, W_gam, W_bet,
                                     ws_f, labp, mup, wtg, wtb);
    k_build<<<37, 256, 0, stream>>>(bn_g, bn_b, b_gam, b_bet, wtg, wtb, mup, ws_f, v2);
    k_main<<<dim3(128, 4, 4), 256, 0, stream>>>(fp, labp, v2, (const float4*)ws_f, out);
}

// Round 2
// 129.182 us; speedup vs baseline: 1.5307x; 1.1552x over previous
//
#include <hip/hip_runtime.h>

#define Bb 4
#define Cc 256
#define Ss 256
#define Hh 128
#define Ww 128
#define Jj 8
#define HWp 16384   // H*W
#define BN_EPS 1e-5f

// ---------------- workspace byte offsets ----------------
#define WS_PS   0          // 1024 f32 partial sums; REUSED after k_build as T[256] float4
#define WS_PQ   4096       // 1024 f32 partial sumsq
#define WS_MU   10240      // mu       4*8*256 f32 (32768 B)
#define WS_LAB  43008      // labels   4*128*128 u8 (65536 B)
#define WS_WTG  108544     // Wt_gamma 2304*256 f32 (2359296 B)
#define WS_WTB  2467840    // Wt_beta  2304*256 f32
#define WS_V2   4827136    // V2 [b][tap][c][16] float2 (gamma,beta) = 1179648 B

// ---- K1 (merged prep): bn-partial | labels | mu | transpose, split by blockIdx ----
__global__ void k_prep(const float* __restrict__ fp, const float* __restrict__ sg,
                       const float* __restrict__ style, const int* __restrict__ mask,
                       const float* __restrict__ Wmu, const float* __restrict__ bmu,
                       const float* __restrict__ Wg, const float* __restrict__ Wb,
                       float* __restrict__ ws_f, unsigned char* __restrict__ labout,
                       float* __restrict__ muout,
                       float* __restrict__ wtg, float* __restrict__ wtb) {
    __shared__ float smem[1056];           // max: transpose tile 32*33
    const int t = threadIdx.x;
    const int blk = blockIdx.x;
    if (blk < 1024) {
        // per-(c,b) partial sums for BN stats
        const int c = blk >> 2, b = blk & 3;
        const float4* s4 = (const float4*)(fp + (size_t)(b * Cc + c) * HWp);
        float sum = 0.f, sq = 0.f;
        #pragma unroll
        for (int k = 0; k < 16; ++k) {
            float4 v = s4[t + k * 256];
            sum += v.x + v.y + v.z + v.w;
            sq  += v.x * v.x + v.y * v.y + v.z * v.z + v.w * v.w;
        }
        float* ls = smem;
        float* lq = smem + 256;
        ls[t] = sum; lq[t] = sq;
        __syncthreads();
        for (int off = 128; off > 0; off >>= 1) {
            if (t < off) { ls[t] += ls[t + off]; lq[t] += lq[t + off]; }
            __syncthreads();
        }
        if (t == 0) { ws_f[blk] = ls[0]; ws_f[1024 + blk] = lq[0]; }
    } else if (blk < 1280) {
        // labels from one-hot sg
        const int i = (blk - 1024) * 256 + t;
        const int b = i >> 14, p = i & (HWp - 1);
        const float* base = sg + (size_t)b * Jj * HWp + p;
        int l = 0;
        #pragma unroll
        for (int j = 0; j < Jj; ++j)
            if (base[(size_t)j * HWp] > 0.5f) l = j;
        labout[i] = (unsigned char)l;
    } else if (blk < 1312) {
        // per-(b,j) style FC + ReLU -> mu
        const int lb = blk - 1280;
        const int b = lb >> 3, j = lb & 7;
        const int sel = (mask[b * Jj + j] == 1) ? j : Jj;
        float* code = smem;
        code[t] = style[(size_t)(b * (Jj + 1) + sel) * Ss + t];
        __syncthreads();
        const float4* wrow = (const float4*)(Wmu + (size_t)(j * Ss + t) * Ss);
        const float4* c4 = (const float4*)code;
        float acc = bmu[j * Ss + t];
        #pragma unroll 8
        for (int s4i = 0; s4i < Ss / 4; ++s4i) {
            float4 w = wrow[s4i]; float4 cv = c4[s4i];
            acc += w.x * cv.x + w.y * cv.y + w.z * cv.z + w.w * cv.w;
        }
        muout[(size_t)lb * Ss + t] = fmaxf(acc, 0.f);
    } else {
        // LDS-tiled transpose [256][2304] -> [2304][256]
        const int local = blk - 1312;            // 0..1151
        const int z = local / 576;
        const int rem = local % 576;
        const int k0 = (rem % 72) * 32;
        const int r0 = (rem / 72) * 32;
        const float* in = z ? Wb : Wg;
        float* outp = z ? wtb : wtg;
        float (*tile)[33] = (float(*)[33])smem;
        const int tx = t & 31, ty = t >> 5;
        #pragma unroll
        for (int i2 = 0; i2 < 4; ++i2)
            tile[ty + 8 * i2][tx] = in[(size_t)(r0 + ty + 8 * i2) * 2304 + k0 + tx];
        __syncthreads();
        #pragma unroll
        for (int i2 = 0; i2 < 4; ++i2)
            outp[(size_t)(k0 + ty + 8 * i2) * 256 + r0 + tx] = tile[tx][ty + 8 * i2];
    }
}

// ---- K2 (merged build): block 0 = BN finalize -> T table; blocks 1..36 = V2 build ----
__global__ void k_build(const float* __restrict__ bn_g, const float* __restrict__ bn_b,
                        const float* __restrict__ bgam, const float* __restrict__ bbet,
                        const float* __restrict__ wtg, const float* __restrict__ wtb,
                        const float* __restrict__ mu, float* __restrict__ ws_f,
                        char* __restrict__ V2) {
    const int t = threadIdx.x;
    if (blockIdx.x == 0) {
        // T[c] = (scale, shift, 1 + b_gamma, b_beta); overwrites PS region (safe:
        // each thread reads exactly floats [4t,4t+4) of PS before writing them)
        float s = 0.f, q = 0.f;
        #pragma unroll
        for (int b = 0; b < 4; ++b) { s += ws_f[t * 4 + b]; q += ws_f[1024 + t * 4 + b]; }
        float mean = s * (1.f / 65536.f);
        float var  = q * (1.f / 65536.f) - mean * mean;
        float sc = bn_g[t] * rsqrtf(var + BN_EPS);
        float sh = bn_b[t] - mean * sc;
        ((float4*)ws_f)[t] = make_float4(sc, sh, 1.f + bgam[t], bbet[t]);
        return;
    }
    const int lb = blockIdx.x - 1;
    const int tap = lb % 9, b = lb / 9;
    __shared__ __align__(16) float ml[Jj * Ss];          // ml[s*8+j] = mu[b][j][s]
    for (int idx = t; idx < Jj * Ss; idx += 256)
        ml[idx] = mu[(size_t)b * Jj * Ss + (size_t)(idx & 7) * Ss + (idx >> 3)];
    __syncthreads();
    float ag[8] = {0,0,0,0,0,0,0,0}, ab[8] = {0,0,0,0,0,0,0,0};
    const float* wpg = wtg + (size_t)tap * 256 + t;
    const float* wpb = wtb + (size_t)tap * 256 + t;
    #pragma unroll 4
    for (int s = 0; s < Ss; ++s) {
        float wg = wpg[(size_t)s * 2304];
        float wb = wpb[(size_t)s * 2304];
        float4 m0 = *(const float4*)&ml[s * 8];
        float4 m1 = *(const float4*)&ml[s * 8 + 4];
        ag[0] += wg * m0.x; ab[0] += wb * m0.x;
        ag[1] += wg * m0.y; ab[1] += wb * m0.y;
        ag[2] += wg * m0.z; ab[2] += wb * m0.z;
        ag[3] += wg * m0.w; ab[3] += wb * m0.w;
        ag[4] += wg * m1.x; ab[4] += wb * m1.x;
        ag[5] += wg * m1.y; ab[5] += wb * m1.y;
        ag[6] += wg * m1.z; ab[6] += wb * m1.z;
        ag[7] += wg * m1.w; ab[7] += wb * m1.w;
    }
    // row (b,tap,c): 16 float2 slots, slot j = (gamma_j, beta_j), slots 8..15 = 0
    float4* row = (float4*)(V2 + ((size_t)((b * 9 + tap) * 256 + t) << 7));
    row[0] = make_float4(ag[0], ab[0], ag[1], ab[1]);
    row[1] = make_float4(ag[2], ab[2], ag[3], ab[3]);
    row[2] = make_float4(ag[4], ab[4], ag[5], ab[5]);
    row[3] = make_float4(ag[6], ab[6], ag[7], ab[7]);
    const float4 z4 = make_float4(0.f, 0.f, 0.f, 0.f);
    row[4] = z4; row[5] = z4; row[6] = z4; row[7] = z4;
}

// ---- K3: fused BN-apply + conv-as-gather + SPADE combine ----
// Batched-MLP version: per batch of 4 channels, issue all 36 gathers + 4 fp loads
// into named registers, sched_barrier(0) pins them above the accumulate group.
__global__ void __launch_bounds__(256, 4) k_main(
    const float* __restrict__ fp, const unsigned char* __restrict__ lab,
    const char* __restrict__ V2, const float4* __restrict__ T,
    float* __restrict__ out) {
    const int h = blockIdx.x, cc = blockIdx.y, b = blockIdx.z;
    __shared__ int labs[3][132];
    __shared__ float4 Tl[64];
    const int t = threadIdx.x;
    if (t < 64) Tl[t] = T[cc * 64 + t];
    for (int idx = t; idx < 3 * 132; idx += 256) {
        const int r = idx / 132, col = idx % 132 - 1;
        const int hh = h - 1 + r;
        int v = 8;                        // OOB sentinel -> zero slot of V2
        if (hh >= 0 && hh < Hh && col >= 0 && col < Ww)
            v = lab[((size_t)b << 14) + (hh << 7) + col];
        labs[r][idx % 132] = v;
    }
    __syncthreads();
    const int w = t & 127;
    const int cs = __builtin_amdgcn_readfirstlane(t >> 7);   // wave-uniform
    const int c0 = cc * 64 + cs * 32;
    const char* Vb = V2 + (size_t)b * 294912 + (size_t)c0 * 128;
    const char* tb[9];
    int voff[9];
    #pragma unroll
    for (int tap = 0; tap < 9; ++tap) {
        tb[tap] = Vb + tap * 32768;                   // uniform base per tap
        voff[tap] = labs[tap / 3][w + tap % 3] * 8;   // per-lane byte offset
    }
    const size_t io = (size_t)(b * Cc + c0) * HWp + (h << 7) + w;
    const float* fpp = fp + io;
    float* outp = out + io;
    #pragma unroll
    for (int cb = 0; cb < 8; ++cb) {
        float2 vv[4][9];
        float f[4];
        #pragma unroll
        for (int ci = 0; ci < 4; ++ci) {
            #pragma unroll
            for (int tap = 0; tap < 9; ++tap)
                vv[ci][tap] = *(const float2*)(tb[tap] + voff[tap] + (cb * 4 + ci) * 128);
            f[ci] = __builtin_nontemporal_load(fpp + (size_t)(cb * 4 + ci) * HWp);
        }
        __builtin_amdgcn_sched_barrier(0);   // keep the 40-load group above its uses
        #pragma unroll
        for (int ci = 0; ci < 4; ++ci) {
            const int c = cb * 4 + ci;
            // tree-sum the 9 taps (short dep chain)
            float g01 = vv[ci][0].x + vv[ci][1].x, g23 = vv[ci][2].x + vv[ci][3].x;
            float g45 = vv[ci][4].x + vv[ci][5].x, g67 = vv[ci][6].x + vv[ci][7].x;
            float e01 = vv[ci][0].y + vv[ci][1].y, e23 = vv[ci][2].y + vv[ci][3].y;
            float e45 = vv[ci][4].y + vv[ci][5].y, e67 = vv[ci][6].y + vv[ci][7].y;
            float g = (g01 + g23) + (g45 + g67) + vv[ci][8].x;
            float e = (e01 + e23) + (e45 + e67) + vv[ci][8].y;
            const float4 tv = Tl[cs * 32 + c];
            const float nf = fmaf(f[ci], tv.x, tv.y);
            const float res = fmaf(nf, tv.z + g, tv.w + e);
            __builtin_nontemporal_store(res, outp + (size_t)c * HWp);
        }
    }
}

extern "C" void kernel_launch(void* const* d_in, const int* in_sizes, int n_in,
                              void* d_out, int out_size, void* d_ws, size_t ws_size,
                              hipStream_t stream) {
    const float* fp      = (const float*)d_in[0];
    const float* sg      = (const float*)d_in[1];
    const float* style   = (const float*)d_in[2];
    const int*   mask    = (const int*)d_in[3];
    const float* bn_g    = (const float*)d_in[4];
    const float* bn_b    = (const float*)d_in[5];
    const float* W_mu    = (const float*)d_in[6];
    const float* b_mu    = (const float*)d_in[7];
    const float* W_gam   = (const float*)d_in[8];
    const float* b_gam   = (const float*)d_in[9];
    const float* W_bet   = (const float*)d_in[10];
    const float* b_bet   = (const float*)d_in[11];
    float* out = (float*)d_out;

    char* ws = (char*)d_ws;
    float*         ws_f  = (float*)ws;
    unsigned char* labp  = (unsigned char*)(ws + WS_LAB);
    float*         mup   = (float*)(ws + WS_MU);
    float*         wtg   = (float*)(ws + WS_WTG);
    float*         wtb   = (float*)(ws + WS_WTB);
    char*          v2    = ws + WS_V2;

    k_prep<<<2464, 256, 0, stream>>>(fp, sg, style, mask, W_mu, b_mu, W_gam, W_bet,
                                     ws_f, labp, mup, wtg, wtb);
    k_build<<<37, 256, 0, stream>>>(bn_g, bn_b, b_gam, b_bet, wtg, wtb, mup, ws_f, v2);
    k_main<<<dim3(128, 4, 4), 256, 0, stream>>>(fp, labp, v2, (const float4*)ws_f, out);
}

// Round 3
// 101.848 us; speedup vs baseline: 1.9415x; 1.2684x over previous
//
#include <hip/hip_runtime.h>

#define Bb 4
#define Cc 256
#define Ss 256
#define Hh 128
#define Ww 128
#define Jj 8
#define HWp 16384   // H*W
#define BN_EPS 1e-5f

// ---------------- workspace byte offsets ----------------
#define WS_PS   0          // 1024 f32 partial sums; REUSED after k_build as T[256] float4
#define WS_PQ   4096       // 1024 f32 partial sumsq
#define WS_MU   10240      // mu       4*8*256 f32 (32768 B)
#define WS_LAB  43008      // labels   4*128*128 u8 (65536 B)
#define WS_WTG  108544     // Wt_gamma 2304*256 f32 (2359296 B)
#define WS_WTB  2467840    // Wt_beta  2304*256 f32
#define WS_VT   4827136    // Vt [gb][b][81 rows][256 ch] f32 = 663552 B

// LDS V-row byte stride (64 ch * 4 B + 16 B pad) -> j-rows spread across banks
#define VROW 272
#define EOFF (81 * VROW)   // 22032: e-array offset inside vbuf

// ---- K1 (merged prep): bn-partial | labels | mu | transpose, split by blockIdx ----
__global__ void k_prep(const float* __restrict__ fp, const float* __restrict__ sg,
                       const float* __restrict__ style, const int* __restrict__ mask,
                       const float* __restrict__ Wmu, const float* __restrict__ bmu,
                       const float* __restrict__ Wg, const float* __restrict__ Wb,
                       float* __restrict__ ws_f, unsigned char* __restrict__ labout,
                       float* __restrict__ muout,
                       float* __restrict__ wtg, float* __restrict__ wtb) {
    __shared__ float smem[1056];           // max: transpose tile 32*33
    const int t = threadIdx.x;
    const int blk = blockIdx.x;
    if (blk < 1024) {
        // per-(c,b) partial sums for BN stats
        const int c = blk >> 2, b = blk & 3;
        const float4* s4 = (const float4*)(fp + (size_t)(b * Cc + c) * HWp);
        float sum = 0.f, sq = 0.f;
        #pragma unroll
        for (int k = 0; k < 16; ++k) {
            float4 v = s4[t + k * 256];
            sum += v.x + v.y + v.z + v.w;
            sq  += v.x * v.x + v.y * v.y + v.z * v.z + v.w * v.w;
        }
        float* ls = smem;
        float* lq = smem + 256;
        ls[t] = sum; lq[t] = sq;
        __syncthreads();
        for (int off = 128; off > 0; off >>= 1) {
            if (t < off) { ls[t] += ls[t + off]; lq[t] += lq[t + off]; }
            __syncthreads();
        }
        if (t == 0) { ws_f[blk] = ls[0]; ws_f[1024 + blk] = lq[0]; }
    } else if (blk < 1280) {
        // labels from one-hot sg
        const int i = (blk - 1024) * 256 + t;
        const int b = i >> 14, p = i & (HWp - 1);
        const float* base = sg + (size_t)b * Jj * HWp + p;
        int l = 0;
        #pragma unroll
        for (int j = 0; j < Jj; ++j)
            if (base[(size_t)j * HWp] > 0.5f) l = j;
        labout[i] = (unsigned char)l;
    } else if (blk < 1312) {
        // per-(b,j) style FC + ReLU -> mu
        const int lb = blk - 1280;
        const int b = lb >> 3, j = lb & 7;
        const int sel = (mask[b * Jj + j] == 1) ? j : Jj;
        float* code = smem;
        code[t] = style[(size_t)(b * (Jj + 1) + sel) * Ss + t];
        __syncthreads();
        const float4* wrow = (const float4*)(Wmu + (size_t)(j * Ss + t) * Ss);
        const float4* c4 = (const float4*)code;
        float acc = bmu[j * Ss + t];
        #pragma unroll 8
        for (int s4i = 0; s4i < Ss / 4; ++s4i) {
            float4 w = wrow[s4i]; float4 cv = c4[s4i];
            acc += w.x * cv.x + w.y * cv.y + w.z * cv.z + w.w * cv.w;
        }
        muout[(size_t)lb * Ss + t] = fmaxf(acc, 0.f);
    } else {
        // LDS-tiled transpose [256][2304] -> [2304][256]
        const int local = blk - 1312;            // 0..1151
        const int z = local / 576;
        const int rem = local % 576;
        const int k0 = (rem % 72) * 32;
        const int r0 = (rem / 72) * 32;
        const float* in = z ? Wb : Wg;
        float* outp = z ? wtb : wtg;
        float (*tile)[33] = (float(*)[33])smem;
        const int tx = t & 31, ty = t >> 5;
        #pragma unroll
        for (int i2 = 0; i2 < 4; ++i2)
            tile[ty + 8 * i2][tx] = in[(size_t)(r0 + ty + 8 * i2) * 2304 + k0 + tx];
        __syncthreads();
        #pragma unroll
        for (int i2 = 0; i2 < 4; ++i2)
            outp[(size_t)(k0 + ty + 8 * i2) * 256 + r0 + tx] = tile[tx][ty + 8 * i2];
    }
}

// ---- K2: blk 0 = BN finalize -> T table; blks 1..72 = Vt build (g/e split) ----
// Vt layout: [z(g/e)][b][tap*9+j][256 ch] f32; row j holds V value for label j, row 8 = 0.
__global__ void k_build(const float* __restrict__ bn_g, const float* __restrict__ bn_b,
                        const float* __restrict__ bgam, const float* __restrict__ bbet,
                        const float* __restrict__ wtg, const float* __restrict__ wtb,
                        const float* __restrict__ mu, float* __restrict__ ws_f,
                        float* __restrict__ vt) {
    const int t = threadIdx.x;
    if (blockIdx.x == 0) {
        // T[c] = (scale, shift, 1 + b_gamma, b_beta); overwrites PS region (safe:
        // each thread reads exactly floats [4t,4t+4) of PS before writing them)
        float s = 0.f, q = 0.f;
        #pragma unroll
        for (int b = 0; b < 4; ++b) { s += ws_f[t * 4 + b]; q += ws_f[1024 + t * 4 + b]; }
        float mean = s * (1.f / 65536.f);
        float var  = q * (1.f / 65536.f) - mean * mean;
        float sc = bn_g[t] * rsqrtf(var + BN_EPS);
        float sh = bn_b[t] - mean * sc;
        ((float4*)ws_f)[t] = make_float4(sc, sh, 1.f + bgam[t], bbet[t]);
        return;
    }
    const int lb = blockIdx.x - 1;          // 0..71
    const int z = lb / 36;
    const int rem = lb % 36;
    const int tap = rem % 9, b = rem / 9;
    const float* Wt = z ? wtb : wtg;
    __shared__ __align__(16) float ml[Jj * Ss];          // ml[s*8+j] = mu[b][j][s]
    for (int idx = t; idx < Jj * Ss; idx += 256)
        ml[idx] = mu[(size_t)b * Jj * Ss + (size_t)(idx & 7) * Ss + (idx >> 3)];
    __syncthreads();
    float ag[8] = {0,0,0,0,0,0,0,0};
    const float* wp = Wt + (size_t)tap * 256 + t;
    #pragma unroll 8
    for (int s = 0; s < Ss; ++s) {
        float wv = wp[(size_t)s * 2304];
        float4 m0 = *(const float4*)&ml[s * 8];
        float4 m1 = *(const float4*)&ml[s * 8 + 4];
        ag[0] += wv * m0.x; ag[1] += wv * m0.y;
        ag[2] += wv * m0.z; ag[3] += wv * m0.w;
        ag[4] += wv * m1.x; ag[5] += wv * m1.y;
        ag[6] += wv * m1.z; ag[7] += wv * m1.w;
    }
    float* Vrow = vt + ((size_t)((z * 4 + b) * 81 + tap * 9) << 8) + t;
    #pragma unroll
    for (int j = 0; j < 8; ++j) Vrow[(size_t)j << 8] = ag[j];
    Vrow[(size_t)8 << 8] = 0.f;             // OOB sentinel row
}

// ---- K3: fused BN-apply + conv-as-gather + SPADE combine, LDS-staged V ----
// Per block: 4 h-rows x 64 channels. V slice (2 arrays x 81 rows x 64 ch) staged to
// LDS via global_load_lds; gathers become conflict-free ds_read_b128 (4 ch/read):
// j-rows are 272 B apart -> 8 random labels hit 8 distinct 16 B bank groups.
__global__ void __launch_bounds__(256, 3) k_main(
    const float* __restrict__ fp, const unsigned char* __restrict__ lab,
    const float* __restrict__ vt, const float4* __restrict__ T,
    float* __restrict__ out) {
    const int h0 = blockIdx.x * 4, cc = blockIdx.y, b = blockIdx.z;
    __shared__ __align__(16) char vbuf[2 * EOFF];   // [g/e][81 rows][272 B]
    __shared__ int labs[6][132];
    __shared__ float4 Tl[64];
    const int t = threadIdx.x;
    const int lane = t & 63;
    const int wid = __builtin_amdgcn_readfirstlane(t >> 6);

    // stage 162 V-rows (256 B each), round-robin across the 4 waves
    for (int r = wid; r < 162; r += 4) {
        const int arr = (r >= 81) ? 1 : 0;
        const int row = r - arr * 81;
        const char* gsrc = (const char*)vt +
            (((size_t)((arr * 4 + b) * 81 + row) << 10) + cc * 256 + lane * 4);
        __builtin_amdgcn_global_load_lds(
            (const __attribute__((address_space(1))) void*)gsrc,
            (__attribute__((address_space(3))) void*)(vbuf + r * VROW), 4, 0, 0);
    }
    if (t < 64) Tl[t] = T[cc * 64 + t];
    for (int idx = t; idx < 6 * 132; idx += 256) {
        const int r = idx / 132, col = idx % 132 - 1;
        const int hh = h0 - 1 + r;
        int v = 8;                        // OOB sentinel -> zero row
        if (hh >= 0 && hh < Hh && col >= 0 && col < Ww)
            v = lab[((size_t)b << 14) + (hh << 7) + col];
        labs[r][idx % 132] = v;
    }
    __syncthreads();

    const int w = t & 127;
    const int cs = t >> 7;                 // 0/1 channel half (wave-uniform)
    const int cbase = cc * 64 + cs * 32;

    for (int hh = 0; hh < 4; ++hh) {
        int vb0[9];
        #pragma unroll
        for (int tap = 0; tap < 9; ++tap) {
            const int j = labs[hh + tap / 3][w + tap % 3];
            vb0[tap] = (tap * 9 + j) * VROW + cs * 128;
        }
        const size_t io = ((size_t)(b * Cc + cbase) << 14) + ((h0 + hh) << 7) + w;
        const float* fpp = fp + io;
        float* outp = out + io;
        #pragma unroll
        for (int cb = 0; cb < 8; ++cb) {
            float4 ga = make_float4(0.f, 0.f, 0.f, 0.f);
            float4 ea = make_float4(0.f, 0.f, 0.f, 0.f);
            #pragma unroll
            for (int tap = 0; tap < 9; ++tap) {
                const float4 vg = *(const float4*)(vbuf + vb0[tap] + cb * 16);
                const float4 ve = *(const float4*)(vbuf + vb0[tap] + EOFF + cb * 16);
                ga.x += vg.x; ga.y += vg.y; ga.z += vg.z; ga.w += vg.w;
                ea.x += ve.x; ea.y += ve.y; ea.z += ve.z; ea.w += ve.w;
            }
            #define APPLY(CI, GV, EV)                                              \
            {                                                                      \
                const int c = cb * 4 + CI;                                         \
                const float4 tv = Tl[cs * 32 + c];                                 \
                const float f = __builtin_nontemporal_load(fpp + (size_t)c * HWp); \
                const float nf = fmaf(f, tv.x, tv.y);                              \
                __builtin_nontemporal_store(fmaf(nf, tv.z + (GV), tv.w + (EV)),    \
                                            outp + (size_t)c * HWp);               \
            }
            APPLY(0, ga.x, ea.x)
            APPLY(1, ga.y, ea.y)
            APPLY(2, ga.z, ea.z)
            APPLY(3, ga.w, ea.w)
            #undef APPLY
        }
    }
}

extern "C" void kernel_launch(void* const* d_in, const int* in_sizes, int n_in,
                              void* d_out, int out_size, void* d_ws, size_t ws_size,
                              hipStream_t stream) {
    const float* fp      = (const float*)d_in[0];
    const float* sg      = (const float*)d_in[1];
    const float* style   = (const float*)d_in[2];
    const int*   mask    = (const int*)d_in[3];
    const float* bn_g    = (const float*)d_in[4];
    const float* bn_b    = (const float*)d_in[5];
    const float* W_mu    = (const float*)d_in[6];
    const float* b_mu    = (const float*)d_in[7];
    const float* W_gam   = (const float*)d_in[8];
    const float* b_gam   = (const float*)d_in[9];
    const float* W_bet   = (const float*)d_in[10];
    const float* b_bet   = (const float*)d_in[11];
    float* out = (float*)d_out;

    char* ws = (char*)d_ws;
    float*         ws_f  = (float*)ws;
    unsigned char* labp  = (unsigned char*)(ws + WS_LAB);
    float*         mup   = (float*)(ws + WS_MU);
    float*         wtg   = (float*)(ws + WS_WTG);
    float*         wtb   = (float*)(ws + WS_WTB);
    float*         vtp   = (float*)(ws + WS_VT);

    k_prep<<<2464, 256, 0, stream>>>(fp, sg, style, mask, W_mu, b_mu, W_gam, W_bet,
                                     ws_f, labp, mup, wtg, wtb);
    k_build<<<73, 256, 0, stream>>>(bn_g, bn_b, b_gam, b_bet, wtg, wtb, mup, ws_f, vtp);
    k_main<<<dim3(32, 4, 4), 256, 0, stream>>>(fp, labp, vtp, (const float4*)ws_f, out);
}

// Round 4
// 71.570 us; speedup vs baseline: 2.7628x; 1.4231x over previous
//
#include <hip/hip_runtime.h>

#define Bb 4
#define Cc 256
#define Ss 256
#define Hh 128
#define Ww 128
#define Jj 8
#define HWp 16384   // H*W
#define BN_EPS 1e-5f

// ---------------- workspace byte offsets ----------------
#define WS_PS   0          // 1024 f32 partial sums; REUSED after k_build as T[256] float4
#define WS_PQ   4096       // 1024 f32 partial sumsq
#define WS_MU   10240      // mu       4*8*256 f32 (32768 B)
#define WS_LAB  43008      // labels   4*128*128 u8 (65536 B)
#define WS_WTG  108544     // Wt_gamma 2304*256 f32 (2359296 B)
#define WS_WTB  2467840    // Wt_beta  2304*256 f32
#define WS_VT   4827136    // Vt [cc8][b4][z2][81 rows][40 f32] = 829440 B (+192 slack)

// Padded V-row: 32 ch * 4 B + 32 B pad = 160 B. j*160B -> j*8 banks: 2-way max (free).
#define VROW 160
#define ZOFF (81 * VROW)       // 12960 B: z=1 (beta) offset inside a (cc,b) slice
#define SLICE (2 * ZOFF)       // 25920 B per (cc,b)
#define VBUF_B 26112           // staged bytes, rounded up to 102 x 256

// ---- K1 (merged prep): bn-partial | labels | mu | transpose, split by blockIdx ----
__global__ void k_prep(const float* __restrict__ fp, const float* __restrict__ sg,
                       const float* __restrict__ style, const int* __restrict__ mask,
                       const float* __restrict__ Wmu, const float* __restrict__ bmu,
                       const float* __restrict__ Wg, const float* __restrict__ Wb,
                       float* __restrict__ ws_f, unsigned char* __restrict__ labout,
                       float* __restrict__ muout,
                       float* __restrict__ wtg, float* __restrict__ wtb) {
    __shared__ float smem[1056];           // max: transpose tile 32*33
    const int t = threadIdx.x;
    const int blk = blockIdx.x;
    if (blk < 1024) {
        // per-(c,b) partial sums for BN stats
        const int c = blk >> 2, b = blk & 3;
        const float4* s4 = (const float4*)(fp + (size_t)(b * Cc + c) * HWp);
        float sum = 0.f, sq = 0.f;
        #pragma unroll
        for (int k = 0; k < 16; ++k) {
            float4 v = s4[t + k * 256];
            sum += v.x + v.y + v.z + v.w;
            sq  += v.x * v.x + v.y * v.y + v.z * v.z + v.w * v.w;
        }
        float* ls = smem;
        float* lq = smem + 256;
        ls[t] = sum; lq[t] = sq;
        __syncthreads();
        for (int off = 128; off > 0; off >>= 1) {
            if (t < off) { ls[t] += ls[t + off]; lq[t] += lq[t + off]; }
            __syncthreads();
        }
        if (t == 0) { ws_f[blk] = ls[0]; ws_f[1024 + blk] = lq[0]; }
    } else if (blk < 1280) {
        // labels from one-hot sg
        const int i = (blk - 1024) * 256 + t;
        const int b = i >> 14, p = i & (HWp - 1);
        const float* base = sg + (size_t)b * Jj * HWp + p;
        int l = 0;
        #pragma unroll
        for (int j = 0; j < Jj; ++j)
            if (base[(size_t)j * HWp] > 0.5f) l = j;
        labout[i] = (unsigned char)l;
    } else if (blk < 1312) {
        // per-(b,j) style FC + ReLU -> mu
        const int lb = blk - 1280;
        const int b = lb >> 3, j = lb & 7;
        const int sel = (mask[b * Jj + j] == 1) ? j : Jj;
        float* code = smem;
        code[t] = style[(size_t)(b * (Jj + 1) + sel) * Ss + t];
        __syncthreads();
        const float4* wrow = (const float4*)(Wmu + (size_t)(j * Ss + t) * Ss);
        const float4* c4 = (const float4*)code;
        float acc = bmu[j * Ss + t];
        #pragma unroll 8
        for (int s4i = 0; s4i < Ss / 4; ++s4i) {
            float4 w = wrow[s4i]; float4 cv = c4[s4i];
            acc += w.x * cv.x + w.y * cv.y + w.z * cv.z + w.w * cv.w;
        }
        muout[(size_t)lb * Ss + t] = fmaxf(acc, 0.f);
    } else {
        // LDS-tiled transpose [256][2304] -> [2304][256]
        const int local = blk - 1312;            // 0..1151
        const int z = local / 576;
        const int rem = local % 576;
        const int k0 = (rem % 72) * 32;
        const int r0 = (rem / 72) * 32;
        const float* in = z ? Wb : Wg;
        float* outp = z ? wtb : wtg;
        float (*tile)[33] = (float(*)[33])smem;
        const int tx = t & 31, ty = t >> 5;
        #pragma unroll
        for (int i2 = 0; i2 < 4; ++i2)
            tile[ty + 8 * i2][tx] = in[(size_t)(r0 + ty + 8 * i2) * 2304 + k0 + tx];
        __syncthreads();
        #pragma unroll
        for (int i2 = 0; i2 < 4; ++i2)
            outp[(size_t)(k0 + ty + 8 * i2) * 256 + r0 + tx] = tile[tx][ty + 8 * i2];
    }
}

// ---- K2: blk 0 = BN finalize -> T table; blks 1..72 = Vt build (g/e split) ----
// Vt layout: [cc][b][z][tap*9+j][40 f32]; row j = V value for label j, row 8 = 0.
__global__ void k_build(const float* __restrict__ bn_g, const float* __restrict__ bn_b,
                        const float* __restrict__ bgam, const float* __restrict__ bbet,
                        const float* __restrict__ wtg, const float* __restrict__ wtb,
                        const float* __restrict__ mu, float* __restrict__ ws_f,
                        float* __restrict__ vt) {
    const int t = threadIdx.x;
    if (blockIdx.x == 0) {
        // T[c] = (scale, shift, 1 + b_gamma, b_beta); overwrites PS region (safe:
        // each thread reads exactly floats [4t,4t+4) of PS before writing them)
        float s = 0.f, q = 0.f;
        #pragma unroll
        for (int b = 0; b < 4; ++b) { s += ws_f[t * 4 + b]; q += ws_f[1024 + t * 4 + b]; }
        float mean = s * (1.f / 65536.f);
        float var  = q * (1.f / 65536.f) - mean * mean;
        float sc = bn_g[t] * rsqrtf(var + BN_EPS);
        float sh = bn_b[t] - mean * sc;
        ((float4*)ws_f)[t] = make_float4(sc, sh, 1.f + bgam[t], bbet[t]);
        return;
    }
    const int lb = blockIdx.x - 1;          // 0..71
    const int z = lb / 36;
    const int rem = lb % 36;
    const int tap = rem % 9, b = rem / 9;
    const float* Wt = z ? wtb : wtg;
    __shared__ __align__(16) float ml[Jj * Ss];          // ml[s*8+j] = mu[b][j][s]
    for (int idx = t; idx < Jj * Ss; idx += 256)
        ml[idx] = mu[(size_t)b * Jj * Ss + (size_t)(idx & 7) * Ss + (idx >> 3)];
    __syncthreads();
    float ag[8] = {0,0,0,0,0,0,0,0};
    const float* wp = Wt + (size_t)tap * 256 + t;
    #pragma unroll 8
    for (int s = 0; s < Ss; ++s) {
        float wv = wp[(size_t)s * 2304];
        float4 m0 = *(const float4*)&ml[s * 8];
        float4 m1 = *(const float4*)&ml[s * 8 + 4];
        ag[0] += wv * m0.x; ag[1] += wv * m0.y;
        ag[2] += wv * m0.z; ag[3] += wv * m0.w;
        ag[4] += wv * m1.x; ag[5] += wv * m1.y;
        ag[6] += wv * m1.z; ag[7] += wv * m1.w;
    }
    // channel c = t: cc group = t>>5, in-group channel = t&31
    const int cc = t >> 5, cl = t & 31;
    float* Vrow = vt + ((size_t)((cc * 4 + b) * 2 + z) * 81 + tap * 9) * 40 + cl;
    #pragma unroll
    for (int j = 0; j < 8; ++j) Vrow[j * 40] = ag[j];
    Vrow[8 * 40] = 0.f;                     // OOB sentinel row
}

// ---- K3: fused BN-apply + conv-as-gather + SPADE combine, LDS-staged V ----
// Per block: 4 h-rows x 32 channels. (cc,b) V-slice (25920 B, pre-padded rows)
// staged verbatim to LDS via 102 contiguous global_load_lds chunks. Gathers are
// ds_read_b128: j rows 160 B apart -> j*8 banks mod 32 -> worst 2-way (free).
__global__ void __launch_bounds__(256, 4) k_main(
    const float* __restrict__ fp, const unsigned char* __restrict__ lab,
    const char* __restrict__ vt, const float4* __restrict__ T,
    float* __restrict__ out) {
    const int h0 = blockIdx.x * 4, cc = blockIdx.y, b = blockIdx.z;
    __shared__ __align__(16) char vbuf[VBUF_B];   // [z][81 rows][160 B]
    __shared__ int labs[6][132];
    __shared__ float4 Tl[32];
    const int t = threadIdx.x;
    const int lane = t & 63;
    const int wid = __builtin_amdgcn_readfirstlane(t >> 6);

    // stage the (cc,b) slice: 102 x 256 B contiguous chunks, round-robin on waves
    {
        const char* slice = vt + (size_t)(cc * 4 + b) * SLICE;
        for (int r = wid; r < 102; r += 4) {
            __builtin_amdgcn_global_load_lds(
                (const __attribute__((address_space(1))) void*)(slice + r * 256 + lane * 4),
                (__attribute__((address_space(3))) void*)(vbuf + r * 256), 4, 0, 0);
        }
    }
    if (t < 32) Tl[t] = T[cc * 32 + t];
    for (int idx = t; idx < 6 * 132; idx += 256) {
        const int r = idx / 132, col = idx % 132 - 1;
        const int hh = h0 - 1 + r;
        int v = 8;                        // OOB sentinel -> zero row
        if (hh >= 0 && hh < Hh && col >= 0 && col < Ww)
            v = lab[((size_t)b << 14) + (hh << 7) + col];
        labs[r][idx % 132] = v;
    }
    __syncthreads();

    const int w = t & 127;
    const int cs = t >> 7;                 // 16-channel half (wave-uniform)
    const int cbase = cc * 32 + cs * 16;

    for (int hh = 0; hh < 4; ++hh) {
        int vb0[9];
        #pragma unroll
        for (int tap = 0; tap < 9; ++tap) {
            const int j = labs[hh + tap / 3][w + tap % 3];
            vb0[tap] = (tap * 9 + j) * VROW + cs * 64;
        }
        const size_t io = ((size_t)(b * Cc + cbase) << 14) + ((h0 + hh) << 7) + w;
        const float* fpp = fp + io;
        float* outp = out + io;
        #pragma unroll
        for (int cb = 0; cb < 4; ++cb) {
            float4 ga = make_float4(0.f, 0.f, 0.f, 0.f);
            float4 ea = make_float4(0.f, 0.f, 0.f, 0.f);
            #pragma unroll
            for (int tap = 0; tap < 9; ++tap) {
                const float4 vg = *(const float4*)(vbuf + vb0[tap] + cb * 16);
                const float4 ve = *(const float4*)(vbuf + ZOFF + vb0[tap] + cb * 16);
                ga.x += vg.x; ga.y += vg.y; ga.z += vg.z; ga.w += vg.w;
                ea.x += ve.x; ea.y += ve.y; ea.z += ve.z; ea.w += ve.w;
            }
            #define APPLY(CI, GV, EV)                                              \
            {                                                                      \
                const int c = cb * 4 + CI;                                         \
                const float4 tv = Tl[cs * 16 + c];                                 \
                const float f = __builtin_nontemporal_load(fpp + (size_t)c * HWp); \
                const float nf = fmaf(f, tv.x, tv.y);                              \
                __builtin_nontemporal_store(fmaf(nf, tv.z + (GV), tv.w + (EV)),    \
                                            outp + (size_t)c * HWp);               \
            }
            APPLY(0, ga.x, ea.x)
            APPLY(1, ga.y, ea.y)
            APPLY(2, ga.z, ea.z)
            APPLY(3, ga.w, ea.w)
            #undef APPLY
        }
    }
}

extern "C" void kernel_launch(void* const* d_in, const int* in_sizes, int n_in,
                              void* d_out, int out_size, void* d_ws, size_t ws_size,
                              hipStream_t stream) {
    const float* fp      = (const float*)d_in[0];
    const float* sg      = (const float*)d_in[1];
    const float* style   = (const float*)d_in[2];
    const int*   mask    = (const int*)d_in[3];
    const float* bn_g    = (const float*)d_in[4];
    const float* bn_b    = (const float*)d_in[5];
    const float* W_mu    = (const float*)d_in[6];
    const float* b_mu    = (const float*)d_in[7];
    const float* W_gam   = (const float*)d_in[8];
    const float* b_gam   = (const float*)d_in[9];
    const float* W_bet   = (const float*)d_in[10];
    const float* b_bet   = (const float*)d_in[11];
    float* out = (float*)d_out;

    char* ws = (char*)d_ws;
    float*         ws_f  = (float*)ws;
    unsigned char* labp  = (unsigned char*)(ws + WS_LAB);
    float*         mup   = (float*)(ws + WS_MU);
    float*         wtg   = (float*)(ws + WS_WTG);
    float*         wtb   = (float*)(ws + WS_WTB);
    float*         vtp   = (float*)(ws + WS_VT);

    k_prep<<<2464, 256, 0, stream>>>(fp, sg, style, mask, W_mu, b_mu, W_gam, W_bet,
                                     ws_f, labp, mup, wtg, wtb);
    k_build<<<73, 256, 0, stream>>>(bn_g, bn_b, b_gam, b_bet, wtg, wtb, mup, ws_f, vtp);
    k_main<<<dim3(32, 8, 4), 256, 0, stream>>>(fp, labp, (const char*)vtp,
                                               (const float4*)ws_f, out);
}